// Round 1
// baseline (88.469 us; speedup 1.0000x reference)
//
#include <hip/hip_runtime.h>
#include <cstdint>
#include <cstddef>

// SequentiallyDependentGater on MI355X.
//
// Plan:
//   K1 proj_kernel   : fw[b,t,0:5] = x[b,t,:] @ W  (memory-bound, 256 MB read)
//                      also stores u and th = log(u/(1-u)) -> fwu rows of 8 f32.
//   K2 map_kernel    : per 128-step chunk, simulate all 16 possible start
//                      windows (4-bit state, one per lane) -> composed
//                      transition map packed in a uint64.
//   K2b combine      : thread the true state (start=0 per batch) through the
//                      chunk maps -> start state per chunk.
//   K3 emit_kernel   : replay each chunk from its known start, emit
//                      logp / p / samp with coalesced writes.
//
// Decision rule everywhere: samp = (logit > th), th = log(u/(1-u)) — monotone-
// equivalent to u < sigmoid(logit). K2 and K3 use the identical inline
// computation so speculative maps and replay agree bit-exactly.

namespace {

constexpr int kB = 8;
constexpr int kS = 8192;
constexpr int kD = 1024;
constexpr int kRows = kB * kS;                 // 65536
constexpr int kT = 128;                        // chunk length (steps)
constexpr int kChunksPerBatch = kS / kT;       // 64
constexpr int kChunks = kB * kChunksPerBatch;  // 512

// window bit i = window[i] (oldest first). logit = fw0 + sum(bit_i * fw[i+1]).
// Row layout in fwu: [fw0, fw1, fw2, fw3] [fw4, u, th, pad]
__device__ __forceinline__ float logit_from_state(unsigned int w,
                                                  const float4& A,
                                                  const float4& Bv) {
  const float s1 = (w & 1u) ? A.y : 0.0f;
  const float s2 = (w & 2u) ? A.z : 0.0f;
  const float s3 = (w & 4u) ? A.w : 0.0f;
  const float s4 = (w & 8u) ? Bv.x : 0.0f;
  return A.x + (((s1 + s2) + s3) + s4);  // matches ref: bias + sum(window*coeffs)
}

}  // namespace

// ---------------------------------------------------------------- K1: proj
// One wave per row (4 KB of x). W kept in 80 VGPRs per lane, loaded once per
// wave (grid-stride loop amortizes). lane's d-range: d = j*256 + lane*4 + k.
__global__ __launch_bounds__(256) void proj_kernel(
    const float* __restrict__ x, const float* __restrict__ W,
    const float* __restrict__ noise, float* __restrict__ fwu) {
  const int lane = threadIdx.x & 63;
  const int wid = (blockIdx.x * (blockDim.x >> 6)) + (threadIdx.x >> 6);
  const int nw = (gridDim.x * blockDim.x) >> 6;

  float wr[4][4][5];
#pragma unroll
  for (int j = 0; j < 4; ++j)
#pragma unroll
    for (int k = 0; k < 4; ++k) {
      const int d = j * 256 + lane * 4 + k;
#pragma unroll
      for (int f = 0; f < 5; ++f) wr[j][k][f] = W[d * 5 + f];
    }

  for (int row = wid; row < kRows; row += nw) {
    const float4* xr = reinterpret_cast<const float4*>(x + (size_t)row * kD);
    float acc[5] = {0.f, 0.f, 0.f, 0.f, 0.f};
#pragma unroll
    for (int j = 0; j < 4; ++j) {
      const float4 v = xr[j * 64 + lane];  // coalesced: 1 KB per wave instr
      const float e[4] = {v.x, v.y, v.z, v.w};
#pragma unroll
      for (int k = 0; k < 4; ++k)
#pragma unroll
        for (int f = 0; f < 5; ++f) acc[f] += e[k] * wr[j][k][f];
    }
    // full-wave butterfly reduce (all lanes end with the sum)
#pragma unroll
    for (int off = 32; off >= 1; off >>= 1)
#pragma unroll
      for (int f = 0; f < 5; ++f) acc[f] += __shfl_xor(acc[f], off);

    if (lane == 0) {
      const float u = noise[row];
      const float th = logf(u / (1.0f - u));  // u==0 -> -inf -> always sample 1
      float4* o = reinterpret_cast<float4*>(fwu + (size_t)row * 8);
      o[0] = make_float4(acc[0], acc[1], acc[2], acc[3]);
      o[1] = make_float4(acc[4], u, th, 0.0f);
    }
  }
}

// ---------------------------------------------------------------- K2: maps
// One wave per 128-step chunk. Lane L tracks the trajectory of start state
// (L & 15). Per-step chain is only: cndmask-sum -> cmp -> shift/or.
__global__ __launch_bounds__(64) void map_kernel(
    const float* __restrict__ fwu, unsigned long long* __restrict__ maps) {
  const int lane = threadIdx.x;
  const int blk = blockIdx.x;  // = b*kChunksPerBatch + c ; rows = blk*kT
  const float* base = fwu + (size_t)blk * kT * 8;
  unsigned int cur = (unsigned int)(lane & 15);
#pragma unroll 8
  for (int i = 0; i < kT; ++i) {
    const float4* p = reinterpret_cast<const float4*>(base + (size_t)i * 8);
    const float4 A = p[0];
    const float4 Bv = p[1];  // Bv.x=fw4, Bv.y=u, Bv.z=th
    const float logit = logit_from_state(cur, A, Bv);
    const unsigned int d = (logit > Bv.z) ? 1u : 0u;
    cur = (cur >> 1) | (d << 3);
  }
  // pack 16-entry end-state map as 4 bitplanes of 16 bits each
  const unsigned long long b0 = __ballot((int)(cur & 1u)) & 0xFFFFull;
  const unsigned long long b1 = __ballot((int)(cur & 2u)) & 0xFFFFull;
  const unsigned long long b2 = __ballot((int)(cur & 4u)) & 0xFFFFull;
  const unsigned long long b3 = __ballot((int)(cur & 8u)) & 0xFFFFull;
  if (lane == 0) maps[blk] = b0 | (b1 << 16) | (b2 << 32) | (b3 << 48);
}

// ---------------------------------------------------------------- K2b: combine
// Thread actual state (window starts at 0 for every batch) through the maps.
__global__ __launch_bounds__(64) void combine_kernel(
    const unsigned long long* __restrict__ maps,
    unsigned int* __restrict__ starts) {
  __shared__ unsigned long long m_lds[kChunks];
  for (int k = threadIdx.x; k < kChunks; k += 64) m_lds[k] = maps[k];
  __syncthreads();
  if (threadIdx.x < kB) {
    const int b = threadIdx.x;
    unsigned int cur = 0;
    for (int c = 0; c < kChunksPerBatch; ++c) {
      const unsigned long long m = m_lds[b * kChunksPerBatch + c];
      starts[b * kChunksPerBatch + c] = cur;
      const unsigned int lo = (unsigned int)m;
      const unsigned int hi = (unsigned int)(m >> 32);
      const unsigned int s0 = (lo >> cur) & 1u;
      const unsigned int s1 = (lo >> (16 + cur)) & 1u;
      const unsigned int s2 = (hi >> cur) & 1u;
      const unsigned int s3 = (hi >> (16 + cur)) & 1u;
      cur = s0 | (s1 << 1) | (s2 << 2) | (s3 << 3);
    }
  }
}

// ---------------------------------------------------------------- K3: emit
// Replay chunk from known start (all lanes redundant), recording the window
// used at step i into lane i's register; then a parallel pass recomputes
// logit/p/logp/samp and writes coalesced.
__global__ __launch_bounds__(64) void emit_kernel(
    const float* __restrict__ fwu, const unsigned int* __restrict__ starts,
    float* __restrict__ out) {
  const int lane = threadIdx.x;
  const int blk = blockIdx.x;
  const int r0 = blk * kT;
  const float* base = fwu + (size_t)r0 * 8;
  unsigned int cur = starts[blk];
  unsigned int wa = 0, wb = 0;
#pragma unroll 8
  for (int i = 0; i < kT; ++i) {
    const float4* p = reinterpret_cast<const float4*>(base + (size_t)i * 8);
    const float4 A = p[0];
    const float4 Bv = p[1];
    if (i == lane) wa = cur;        // window used at step lane
    if (i == lane + 64) wb = cur;   // window used at step lane+64
    const float logit = logit_from_state(cur, A, Bv);
    cur = (cur >> 1) | ((logit > Bv.z) ? 8u : 0u);
  }
#pragma unroll
  for (int h = 0; h < 2; ++h) {
    const int i = lane + h * 64;
    const unsigned int w = h ? wb : wa;
    const int row = r0 + i;
    const float4* p = reinterpret_cast<const float4*>(fwu + (size_t)row * 8);
    const float4 A = p[0];
    const float4 Bv = p[1];
    const float logit = logit_from_state(w, A, Bv);  // identical recompute
    const float pr = 1.0f / (1.0f + expf(-logit));
    const float lp = fminf(logit, 0.0f) - log1pf(expf(-fabsf(logit)));
    out[row] = lp;                                    // gate_logits (= logp)
    out[kRows + row] = pr;                            // gate_probs
    out[2 * kRows + row] = (logit > Bv.z) ? 1.0f : 0.0f;  // gate_samples
  }
}

extern "C" void kernel_launch(void* const* d_in, const int* in_sizes, int n_in,
                              void* d_out, int out_size, void* d_ws,
                              size_t ws_size, hipStream_t stream) {
  const float* x = (const float*)d_in[0];
  const float* W = (const float*)d_in[1];
  const float* noise = (const float*)d_in[2];
  float* out = (float*)d_out;

  // ws layout: fwu (65536*8 f32 = 2 MB) | maps (512 u64 = 4 KB) | starts (2 KB)
  float* fwu = (float*)d_ws;
  unsigned long long* maps =
      (unsigned long long*)((char*)d_ws + (size_t)kRows * 8 * sizeof(float));
  unsigned int* starts =
      (unsigned int*)((char*)maps + (size_t)kChunks * sizeof(unsigned long long));

  proj_kernel<<<2048, 256, 0, stream>>>(x, W, noise, fwu);
  map_kernel<<<kChunks, 64, 0, stream>>>(fwu, maps);
  combine_kernel<<<1, 64, 0, stream>>>(maps, starts);
  emit_kernel<<<kChunks, 64, 0, stream>>>(fwu, starts, out);
}

// Round 2
// 63.378 us; speedup vs baseline: 1.3959x; 1.3959x over previous
//
#include <hip/hip_runtime.h>
#include <cstdint>
#include <cstddef>

// SequentiallyDependentGater on MI355X — R2.
//
//   K1 proj    : fw[row,0:5] = x[row,:] @ W ; also u, th=log(u/(1-u)).
//                W staged via LDS (coalesced) -> per-lane regs; wave-per-row,
//                4x float4 loads/lane, butterfly reduce. Memory-bound.
//   K2 map     : per 64-step chunk, simulate all 16 start states (lane&15),
//                record per-state decision bitstring traj (u64) and the
//                16-entry end-state map (u64, 4-bit entries).
//   K3 combine : parallel Hillis-Steele scan of chunk maps per batch
//                (compose(a,b)[s] = b[a[s]]) -> start state per chunk.
//   K4 emit    : fully parallel: window at step i = ((start | traj<<4)>>i)&15,
//                samp = traj bit i. No serial chain. Coalesced outputs.
//
// Decision rule everywhere: samp = (logit > th), th = log(u/(1-u)); map is the
// single point where decisions are computed, so map/emit agree bit-exactly.

namespace {

constexpr int kB = 8;
constexpr int kS = 8192;
constexpr int kD = 1024;
constexpr int kRows = kB * kS;             // 65536
constexpr int kT = 64;                     // chunk length (steps)
constexpr int kCPB = kS / kT;              // 128 chunks per batch
constexpr int kChunks = kB * kCPB;         // 1024
constexpr unsigned long long kIdMap = 0xFEDCBA9876543210ull;

// window bit i = window[i] (oldest first). logit = fw0 + sum(bit_i * fw[i+1]).
// fwu row layout: [fw0, fw1, fw2, fw3] [fw4, u, th, pad]
__device__ __forceinline__ float logit_from_state(unsigned int w,
                                                  const float4& A,
                                                  const float4& Bv) {
  const float s1 = (w & 1u) ? A.y : 0.0f;
  const float s2 = (w & 2u) ? A.z : 0.0f;
  const float s3 = (w & 4u) ? A.w : 0.0f;
  const float s4 = (w & 8u) ? Bv.x : 0.0f;
  return A.x + (((s1 + s2) + s3) + s4);
}

// 16-entry 4-bit maps packed in u64; result[s] = b[a[s]] ("a then b").
__device__ __forceinline__ unsigned long long compose(unsigned long long a,
                                                      unsigned long long b) {
  unsigned long long r = 0;
#pragma unroll
  for (int s = 0; s < 16; ++s) {
    const unsigned int e = (unsigned int)(a >> (4 * s)) & 15u;
    r |= ((b >> (4 * e)) & 15ull) << (4 * s);
  }
  return r;
}

}  // namespace

// ---------------------------------------------------------------- K1: proj
// 1024 blocks x 256 (4 blocks/CU, 16 waves/CU). W: global->LDS coalesced,
// then per-lane regs (one-time, off the VMEM path). Wave per row, 16 rows/wave.
__global__ __launch_bounds__(256, 4) void proj_kernel(
    const float* __restrict__ x, const float* __restrict__ W,
    const float* __restrict__ noise, float* __restrict__ fwu) {
  __shared__ float Wl[kD * 5];
  const int tid = threadIdx.x;

  const float4* W4 = reinterpret_cast<const float4*>(W);
  float4* Wl4 = reinterpret_cast<float4*>(Wl);
#pragma unroll
  for (int i = 0; i < 5; ++i) Wl4[tid + 256 * i] = W4[tid + 256 * i];
  __syncthreads();

  const int lane = tid & 63;
  const int wid = blockIdx.x * 4 + (tid >> 6);
  const int nw = gridDim.x * 4;

  float wr[4][4][5];
#pragma unroll
  for (int j = 0; j < 4; ++j)
#pragma unroll
    for (int k = 0; k < 4; ++k) {
      const int d = j * 256 + lane * 4 + k;
#pragma unroll
      for (int f = 0; f < 5; ++f) wr[j][k][f] = Wl[d * 5 + f];
    }

  for (int row = wid; row < kRows; row += nw) {
    const float4* xr = reinterpret_cast<const float4*>(x + (size_t)row * kD);
    float acc[5] = {0.f, 0.f, 0.f, 0.f, 0.f};
#pragma unroll
    for (int j = 0; j < 4; ++j) {
      const float4 v = xr[j * 64 + lane];  // coalesced 1 KB per wave instr
      const float e[4] = {v.x, v.y, v.z, v.w};
#pragma unroll
      for (int k = 0; k < 4; ++k)
#pragma unroll
        for (int f = 0; f < 5; ++f) acc[f] += e[k] * wr[j][k][f];
    }
#pragma unroll
    for (int off = 32; off >= 1; off >>= 1)
#pragma unroll
      for (int f = 0; f < 5; ++f) acc[f] += __shfl_xor(acc[f], off);

    if (lane == 0) {
      const float u = noise[row];
      const float th = logf(u / (1.0f - u));  // u==0 -> -inf -> always sample 1
      float4* o = reinterpret_cast<float4*>(fwu + (size_t)row * 8);
      o[0] = make_float4(acc[0], acc[1], acc[2], acc[3]);
      o[1] = make_float4(acc[4], u, th, 0.0f);
    }
  }
}

// ---------------------------------------------------------------- K2: map
// One wave per 64-step chunk. Lane L tracks start state (L&15); records the
// decision bitstring traj and end state.
__global__ __launch_bounds__(64) void map_kernel(
    const float* __restrict__ fwu, unsigned long long* __restrict__ trajbuf,
    unsigned long long* __restrict__ maps) {
  __shared__ unsigned int end_sh[16];
  const int lane = threadIdx.x;
  const int chunk = blockIdx.x;
  const float* base = fwu + (size_t)chunk * kT * 8;

  unsigned int cur = (unsigned int)(lane & 15);
  unsigned long long traj = 0;
#pragma unroll 8
  for (int i = 0; i < kT; ++i) {
    const float4* p = reinterpret_cast<const float4*>(base + (size_t)i * 8);
    const float4 A = p[0];
    const float4 Bv = p[1];  // Bv.x=fw4, Bv.y=u, Bv.z=th
    const unsigned int d = (logit_from_state(cur, A, Bv) > Bv.z) ? 1u : 0u;
    traj |= (unsigned long long)d << i;
    cur = (cur >> 1) | (d << 3);
  }
  if (lane < 16) {
    trajbuf[(size_t)chunk * 16 + lane] = traj;
    end_sh[lane] = cur;
  }
  __syncthreads();
  if (lane == 0) {
    unsigned long long m = 0;
#pragma unroll
    for (int s = 0; s < 16; ++s)
      m |= (unsigned long long)(end_sh[s] & 15u) << (4 * s);
    maps[chunk] = m;
  }
}

// ---------------------------------------------------------------- K3: combine
// 8 waves (one per batch). Lane L owns chunks 2L,2L+1; pairwise compose, then
// Hillis-Steele inclusive scan; exclusive prefix applied to state 0.
__global__ __launch_bounds__(512) void combine_kernel(
    const unsigned long long* __restrict__ maps,
    unsigned int* __restrict__ starts) {
  const int b = threadIdx.x >> 6;
  const int L = threadIdx.x & 63;
  const unsigned long long m0 = maps[b * kCPB + 2 * L];
  const unsigned long long m1 = maps[b * kCPB + 2 * L + 1];
  unsigned long long scan = compose(m0, m1);
#pragma unroll
  for (int off = 1; off < 64; off <<= 1) {
    const unsigned long long prev = __shfl_up(scan, off);
    if (L >= off) scan = compose(prev, scan);
  }
  unsigned long long pref = __shfl_up(scan, 1);
  if (L == 0) pref = kIdMap;
  const unsigned int s0 = (unsigned int)(pref & 15ull);  // state before 2L
  starts[b * kCPB + 2 * L] = s0;
  starts[b * kCPB + 2 * L + 1] = (unsigned int)((m0 >> (4 * s0)) & 15ull);
}

// ---------------------------------------------------------------- K4: emit
// Fully parallel: wave per chunk (4 waves/block). seq = start | traj<<4;
// window at step i = (seq >> i) & 15; samp = traj bit i.
__global__ __launch_bounds__(256) void emit_kernel(
    const float* __restrict__ fwu, const unsigned int* __restrict__ starts,
    const unsigned long long* __restrict__ trajbuf, float* __restrict__ out) {
  const int lane = threadIdx.x & 63;
  const int chunk = blockIdx.x * 4 + (threadIdx.x >> 6);
  const unsigned int st = starts[chunk];
  const unsigned long long traj = trajbuf[(size_t)chunk * 16 + st];
  const int row = chunk * kT + lane;

  const float4* p = reinterpret_cast<const float4*>(fwu + (size_t)row * 8);
  const float4 A = p[0];
  const float4 Bv = p[1];

  unsigned int w;
  if (lane >= 4)
    w = (unsigned int)(traj >> (lane - 4)) & 15u;
  else
    w = ((st >> lane) | ((unsigned int)traj << (4 - lane))) & 15u;

  const float logit = logit_from_state(w, A, Bv);
  const float pr = 1.0f / (1.0f + expf(-logit));
  const float lp = fminf(logit, 0.0f) - log1pf(expf(-fabsf(logit)));
  out[row] = lp;                                   // gate_logits (= logp)
  out[kRows + row] = pr;                           // gate_probs
  out[2 * kRows + row] = (float)((traj >> lane) & 1ull);  // gate_samples
}

extern "C" void kernel_launch(void* const* d_in, const int* in_sizes, int n_in,
                              void* d_out, int out_size, void* d_ws,
                              size_t ws_size, hipStream_t stream) {
  const float* x = (const float*)d_in[0];
  const float* W = (const float*)d_in[1];
  const float* noise = (const float*)d_in[2];
  float* out = (float*)d_out;

  // ws layout: fwu (65536*8 f32 = 2 MB) | trajbuf (1024*16 u64 = 128 KB)
  //            | maps (1024 u64 = 8 KB) | starts (1024 u32 = 4 KB)
  float* fwu = (float*)d_ws;
  unsigned long long* trajbuf =
      (unsigned long long*)((char*)d_ws + (size_t)kRows * 8 * sizeof(float));
  unsigned long long* maps =
      (unsigned long long*)((char*)trajbuf +
                            (size_t)kChunks * 16 * sizeof(unsigned long long));
  unsigned int* starts =
      (unsigned int*)((char*)maps + (size_t)kChunks * sizeof(unsigned long long));

  proj_kernel<<<1024, 256, 0, stream>>>(x, W, noise, fwu);
  map_kernel<<<kChunks, 64, 0, stream>>>(fwu, trajbuf, maps);
  combine_kernel<<<1, 512, 0, stream>>>(maps, starts);
  emit_kernel<<<kChunks / 4, 256, 0, stream>>>(fwu, starts, trajbuf, out);
}

// Round 3
// 60.351 us; speedup vs baseline: 1.4659x; 1.0502x over previous
//
#include <hip/hip_runtime.h>
#include <cstdint>
#include <cstddef>

// SequentiallyDependentGater on MI355X — R3: 2-kernel fused pipeline.
//
//   K1 proj_map : block = one 64-step chunk (64 rows of x).
//                 - 4 waves project 16 rows each: fw = x_row @ W (coalesced
//                   float4, W staged LDS->VGPR, butterfly reduce), u,
//                   th = log(u/(1-u)); rows -> LDS + global fwu.
//                 - wave 0 then simulates all 16 possible start windows
//                   (lane&15) for the 64 steps from LDS, records per-state
//                   decision bitstrings traj (u64) and the 16-entry end-state
//                   map (u64, 4-bit entries, packed via ballot bitplanes).
//                 Sim is hidden under other resident blocks' HBM streaming.
//   K2 scan_emit: block = 4 chunks. Wave 0 redundantly Hillis-Steele-scans
//                 its batch's 128 chunk maps (compose(a,b)[s]=b[a[s]]) ->
//                 starts in LDS; then fully parallel emit: window at step i
//                 = ((start | traj<<4) >> i) & 15, samp = traj bit i.
//
// Decision rule everywhere: samp = (logit > th), th = log(u/(1-u)) — monotone-
// equivalent to u < sigmoid(logit) incl. ties. K1's sim is the single point
// where decisions are made; K2 recomputes logit from identical fwu bits with
// the identical pure-add/select expression (bit-exact, no FMA contraction).

namespace {

constexpr int kB = 8;
constexpr int kS = 8192;
constexpr int kD = 1024;
constexpr int kRows = kB * kS;             // 65536
constexpr int kT = 64;                     // chunk length (steps)
constexpr int kCPB = kS / kT;              // 128 chunks per batch
constexpr int kChunks = kB * kCPB;         // 1024
constexpr unsigned long long kIdMap = 0xFEDCBA9876543210ull;

// window bit i = window[i] (oldest first). logit = fw0 + sum(bit_i * fw[i+1]).
// fwu row layout: [fw0, fw1, fw2, fw3] [fw4, u, th, pad]
__device__ __forceinline__ float logit_from_state(unsigned int w,
                                                  const float4& A,
                                                  const float4& Bv) {
  const float s1 = (w & 1u) ? A.y : 0.0f;
  const float s2 = (w & 2u) ? A.z : 0.0f;
  const float s3 = (w & 4u) ? A.w : 0.0f;
  const float s4 = (w & 8u) ? Bv.x : 0.0f;
  return A.x + (((s1 + s2) + s3) + s4);
}

// 16-entry 4-bit maps packed in u64; result[s] = b[a[s]] ("a then b").
__device__ __forceinline__ unsigned long long compose(unsigned long long a,
                                                      unsigned long long b) {
  unsigned long long r = 0;
#pragma unroll
  for (int s = 0; s < 16; ++s) {
    const unsigned int e = (unsigned int)(a >> (4 * s)) & 15u;
    r |= ((b >> (4 * e)) & 15ull) << (4 * s);
  }
  return r;
}

}  // namespace

// ---------------------------------------------------------------- K1
__global__ __launch_bounds__(256, 4) void proj_map_kernel(
    const float* __restrict__ x, const float* __restrict__ W,
    const float* __restrict__ noise, float* __restrict__ fwu,
    unsigned long long* __restrict__ trajbuf,
    unsigned long long* __restrict__ maps) {
  __shared__ float Wl[kD * 5];    // 20 KB
  __shared__ float fl[kT * 8];    // 2 KB chunk-local fwu
  const int tid = threadIdx.x;

  // Stage W coalesced into LDS, then into per-lane registers.
  const float4* W4 = reinterpret_cast<const float4*>(W);
  float4* Wl4 = reinterpret_cast<float4*>(Wl);
#pragma unroll
  for (int i = 0; i < 5; ++i) Wl4[tid + 256 * i] = W4[tid + 256 * i];
  __syncthreads();

  const int lane = tid & 63;
  const int wv = tid >> 6;
  const int chunk = blockIdx.x;
  const int r0 = chunk * kT;

  float wr[4][4][5];
#pragma unroll
  for (int j = 0; j < 4; ++j)
#pragma unroll
    for (int k = 0; k < 4; ++k) {
      const int d = j * 256 + lane * 4 + k;
#pragma unroll
      for (int f = 0; f < 5; ++f) wr[j][k][f] = Wl[d * 5 + f];
    }

  // Each wave projects 16 consecutive rows of this block's chunk.
#pragma unroll 1
  for (int t = 0; t < 16; ++t) {
    const int rl = wv * 16 + t;          // row within chunk
    const int row = r0 + rl;
    const float4* xr = reinterpret_cast<const float4*>(x + (size_t)row * kD);
    float acc[5] = {0.f, 0.f, 0.f, 0.f, 0.f};
#pragma unroll
    for (int j = 0; j < 4; ++j) {
      const float4 v = xr[j * 64 + lane];  // coalesced 1 KB per wave instr
      const float e[4] = {v.x, v.y, v.z, v.w};
#pragma unroll
      for (int k = 0; k < 4; ++k)
#pragma unroll
        for (int f = 0; f < 5; ++f) acc[f] += e[k] * wr[j][k][f];
    }
#pragma unroll
    for (int off = 32; off >= 1; off >>= 1)
#pragma unroll
      for (int f = 0; f < 5; ++f) acc[f] += __shfl_xor(acc[f], off);

    if (lane == 0) {
      const float u = noise[row];
      const float th = logf(u / (1.0f - u));  // u==0 -> -inf -> always samp 1
      const float4 o0 = make_float4(acc[0], acc[1], acc[2], acc[3]);
      const float4 o1 = make_float4(acc[4], u, th, 0.0f);
      float4* og = reinterpret_cast<float4*>(fwu + (size_t)row * 8);
      og[0] = o0;
      og[1] = o1;
      float4* ol = reinterpret_cast<float4*>(&fl[rl * 8]);
      ol[0] = o0;
      ol[1] = o1;
    }
  }
  __syncthreads();

  // Wave 0: speculative 16-state simulation of the 64 steps from LDS.
  if (wv == 0) {
    unsigned int cur = (unsigned int)(lane & 15);
    unsigned long long traj = 0;
#pragma unroll 8
    for (int i = 0; i < kT; ++i) {
      const float4* p = reinterpret_cast<const float4*>(&fl[i * 8]);
      const float4 A = p[0];
      const float4 Bv = p[1];  // Bv.x=fw4, Bv.y=u, Bv.z=th
      const unsigned int d = (logit_from_state(cur, A, Bv) > Bv.z) ? 1u : 0u;
      traj |= (unsigned long long)d << i;
      cur = (cur >> 1) | (d << 3);
    }
    if (lane < 16) trajbuf[(size_t)chunk * 16 + lane] = traj;
    // Pack end-state map via ballot bitplanes (lanes 16+ mirror lane&15).
    const unsigned long long b0 = __ballot((int)(cur & 1u));
    const unsigned long long b1 = __ballot((int)(cur & 2u));
    const unsigned long long b2 = __ballot((int)(cur & 4u));
    const unsigned long long b3 = __ballot((int)(cur & 8u));
    if (lane == 0) {
      unsigned long long m = 0;
#pragma unroll
      for (int s = 0; s < 16; ++s) {
        const unsigned long long e =
            ((b0 >> s) & 1ull) | (((b1 >> s) & 1ull) << 1) |
            (((b2 >> s) & 1ull) << 2) | (((b3 >> s) & 1ull) << 3);
        m |= e << (4 * s);
      }
      maps[chunk] = m;
    }
  }
}

// ---------------------------------------------------------------- K2
// Block = 4 chunks (all within one batch since 4 | 128). Wave 0 redundantly
// scans the batch's 128 chunk maps -> starts in LDS; then parallel emit.
__global__ __launch_bounds__(256) void scan_emit_kernel(
    const float* __restrict__ fwu, const unsigned long long* __restrict__ maps,
    const unsigned long long* __restrict__ trajbuf, float* __restrict__ out) {
  __shared__ unsigned int starts_lds[kCPB];
  const int tid = threadIdx.x;
  const int lane = tid & 63;
  const int wv = tid >> 6;
  const int c0 = blockIdx.x * 4;
  const int b = c0 / kCPB;

  if (wv == 0) {
    const int L = lane;
    const unsigned long long m0 = maps[b * kCPB + 2 * L];
    const unsigned long long m1 = maps[b * kCPB + 2 * L + 1];
    unsigned long long scan = compose(m0, m1);
#pragma unroll
    for (int off = 1; off < 64; off <<= 1) {
      const unsigned long long prev = __shfl_up(scan, off);
      if (L >= off) scan = compose(prev, scan);
    }
    unsigned long long pref = __shfl_up(scan, 1);
    if (L == 0) pref = kIdMap;
    const unsigned int s0 = (unsigned int)(pref & 15ull);  // state before 2L
    starts_lds[2 * L] = s0;
    starts_lds[2 * L + 1] = (unsigned int)((m0 >> (4 * s0)) & 15ull);
  }
  __syncthreads();

  const int chunk = c0 + wv;
  const unsigned int st = starts_lds[chunk & (kCPB - 1)];
  const unsigned long long traj = trajbuf[(size_t)chunk * 16 + st];
  const int row = chunk * kT + lane;

  const float4* p = reinterpret_cast<const float4*>(fwu + (size_t)row * 8);
  const float4 A = p[0];
  const float4 Bv = p[1];

  unsigned int w;
  if (lane >= 4)
    w = (unsigned int)(traj >> (lane - 4)) & 15u;
  else
    w = ((st >> lane) | ((unsigned int)traj << (4 - lane))) & 15u;

  const float logit = logit_from_state(w, A, Bv);  // identical recompute
  const float pr = 1.0f / (1.0f + expf(-logit));
  const float lp = fminf(logit, 0.0f) - log1pf(expf(-fabsf(logit)));
  out[row] = lp;                                        // gate_logits (= logp)
  out[kRows + row] = pr;                                // gate_probs
  out[2 * kRows + row] = (float)((traj >> lane) & 1ull);  // gate_samples
}

extern "C" void kernel_launch(void* const* d_in, const int* in_sizes, int n_in,
                              void* d_out, int out_size, void* d_ws,
                              size_t ws_size, hipStream_t stream) {
  const float* x = (const float*)d_in[0];
  const float* W = (const float*)d_in[1];
  const float* noise = (const float*)d_in[2];
  float* out = (float*)d_out;

  // ws layout: fwu (65536*8 f32 = 2 MB) | trajbuf (1024*16 u64 = 128 KB)
  //            | maps (1024 u64 = 8 KB)
  float* fwu = (float*)d_ws;
  unsigned long long* trajbuf =
      (unsigned long long*)((char*)d_ws + (size_t)kRows * 8 * sizeof(float));
  unsigned long long* maps =
      (unsigned long long*)((char*)trajbuf +
                            (size_t)kChunks * 16 * sizeof(unsigned long long));

  proj_map_kernel<<<kChunks, 256, 0, stream>>>(x, W, noise, fwu, trajbuf, maps);
  scan_emit_kernel<<<kChunks / 4, 256, 0, stream>>>(fwu, maps, trajbuf, out);
}